// Round 1
// baseline (232.275 us; speedup 1.0000x reference)
//
#include <hip/hip_runtime.h>
#include <hip/hip_bf16.h>

#define AS1 __attribute__((address_space(1)))
#define AS3 __attribute__((address_space(3)))

typedef __attribute__((ext_vector_type(8))) short bf16x8;
typedef __attribute__((ext_vector_type(4))) float f32x4;

#define KTOT 9216   // K = 1024 * 9, also the coeff row stride (O*9)
#define NOUT 1024

__device__ __forceinline__ void gll16(const void* g, void* l) {
    __builtin_amdgcn_global_load_lds((const AS1 void*)g, (AS3 void*)l, 16, 0, 0);
}

__device__ __forceinline__ unsigned short f2bf(float f) {
    union { __hip_bfloat16 h; unsigned short u; } cv;
    cv.h = __float2bfloat16(f);
    return cv.u;
}

__device__ __forceinline__ float fast_tanhf(float v) {
    float e = __expf(2.0f * v);
    return 1.0f - 2.0f / (e + 1.0f);
}

// ---------------------------------------------------------------------------
// Prep: coeffs (I=1024, O=1024, 9) f32  ->  Wt[n][k] bf16, k = d*1024 + i,
// with k pre-swizzled within each 64-chunk: pos = kc ^ ((n&7)<<3), so that a
// LINEAR global_load_lds of a [128 n][64 k] tile lands XOR-swizzled in LDS.
// Block: n-tile 32, i-tile 64. Grid 512.
// ---------------------------------------------------------------------------
__global__ void __launch_bounds__(256) prep_kernel(const float* __restrict__ cc,
                                                   unsigned short* __restrict__ Wt) {
    __shared__ unsigned short T[288 * 68];  // [f = nl*9 + d][il], padded to 68
    const int t  = threadIdx.x;
    const int n0 = (blockIdx.x & 31) * 32;
    const int i0 = (blockIdx.x >> 5) * 64;

    for (int il = 0; il < 64; ++il) {
        const float* src = cc + (size_t)(i0 + il) * KTOT + (size_t)n0 * 9;
        for (int f = t; f < 288; f += 256)
            T[f * 68 + il] = f2bf(src[f]);
    }
    __syncthreads();

    // 288 chunks of (nl, d); each chunk = 64 elements = 128 B contiguous out.
    for (int it = 0; it < 18; ++it) {
        const int chunk = it * 16 + (t >> 4);
        const int nl = chunk / 9;
        const int d  = chunk - nl * 9;
        const int n  = n0 + nl;
        const int e0 = (t & 15) * 4;               // output positions e0..e0+3
        const int isrc = e0 ^ ((n & 7) << 3);      // source i-locals (consecutive)
        ushort4 v = *(const ushort4*)&T[chunk * 68 + isrc];
        *(ushort4*)(Wt + (size_t)n * KTOT + d * 1024 + i0 + e0) = v;
    }
}

// ---------------------------------------------------------------------------
// Fused GEMM: out[8192][1024] = Cheby(tanh(x)) @ Wt^T
// 128x128 tile, 256 threads (4 waves, each 64x64), BK=64 per (i-chunk, d) step.
// A generated in-register (fp32 recurrence), ds_written XOR-swizzled;
// B staged via global_load_lds (pre-swizzled in ws).
// ---------------------------------------------------------------------------
__global__ void __launch_bounds__(256, 2)
cheby_gemm(const float* __restrict__ x, const unsigned short* __restrict__ Wt,
           float* __restrict__ out) {
    __shared__ unsigned short Asub[128 * 64];  // 16 KB, [row][kc] swizzled
    __shared__ unsigned short Bsub[128 * 64];  // 16 KB, [n][kc] swizzled

    const int id   = blockIdx.x;       // 512 blocks
    const int bcol = (id & 7) * 128;   // col strip per XCD (round-robin dispatch)
    const int brow = (id >> 3) * 128;
    const int t    = threadIdx.x;
    const int lane = t & 63;
    const int w    = t >> 6;
    const int wr   = (w >> 1) * 64;
    const int wc   = (w & 1) * 64;
    const int l15  = lane & 15;
    const int lhi  = lane >> 4;

    // generation mapping: thread covers rows gr+16p (p=0..7), i-quad gi0..gi0+3
    const int gi0 = (t & 15) * 4;
    const int gr  = t >> 4;

    // B staging mapping
    const int bn_loc = t >> 3;        // 0..31
    const int bpos   = (t & 7) * 8;   // elements (16 B)

    f32x4 acc[4][4] = {};

    float x2[8][4], Tp[8][4], Tpp[8][4];

    unsigned awoff[8];
#pragma unroll
    for (int p = 0; p < 8; ++p) {
        const int r = gr + 16 * p;
        awoff[p] = r * 128 + ((gi0 * 2) ^ ((r & 7) << 4));
    }

    for (int ic = 0; ic < 16; ++ic) {
        // load x sub-tile, tanh once per chunk; store 2*tanh
#pragma unroll
        for (int p = 0; p < 8; ++p) {
            const float4 v = *(const float4*)(x + (size_t)(brow + gr + 16 * p) * 1024
                                              + ic * 64 + gi0);
            x2[p][0] = 2.0f * fast_tanhf(v.x);
            x2[p][1] = 2.0f * fast_tanhf(v.y);
            x2[p][2] = 2.0f * fast_tanhf(v.z);
            x2[p][3] = 2.0f * fast_tanhf(v.w);
        }
#pragma unroll
        for (int d = 0; d < 9; ++d) {
            __syncthreads();  // previous MFMA phase done reading LDS

            // stage B: 4 chunks x (64 lanes x 16 B), linear dest per wave
            const int kb = d * 1024 + ic * 64;
#pragma unroll
            for (int c = 0; c < 4; ++c) {
                const unsigned short* src =
                    Wt + (size_t)(bcol + c * 32 + bn_loc) * KTOT + kb + bpos;
                gll16(src, (char*)Bsub + c * 4096 + w * 1024);
            }

            // generate + write A (T_d values), swizzled
#pragma unroll
            for (int p = 0; p < 8; ++p) {
                ushort4 pk;
                unsigned short* pks = (unsigned short*)&pk;
#pragma unroll
                for (int j = 0; j < 4; ++j) {
                    float cur;
                    if (d == 0) {
                        cur = 1.0f;
                    } else if (d == 1) {
                        cur = 0.5f * x2[p][j];
                        Tp[p][j] = cur;
                        Tpp[p][j] = 1.0f;
                    } else {
                        cur = __builtin_fmaf(x2[p][j], Tp[p][j], -Tpp[p][j]);
                        Tpp[p][j] = Tp[p][j];
                        Tp[p][j] = cur;
                    }
                    pks[j] = f2bf(cur);
                }
                *(ushort4*)((char*)Asub + awoff[p]) = pk;
            }

            __syncthreads();  // A written, B landed (compiler drains cnts)

            // MFMA phase: BK=64 -> 2 k-steps of 32
#pragma unroll
            for (int ks = 0; ks < 2; ++ks) {
                bf16x8 af[4], bfr[4];
#pragma unroll
                for (int mf = 0; mf < 4; ++mf) {
                    const int row = wr + mf * 16 + l15;
                    af[mf] = *(const bf16x8*)((const char*)Asub + row * 128 +
                              ((ks * 64 + lhi * 16) ^ ((row & 7) << 4)));
                }
#pragma unroll
                for (int nf = 0; nf < 4; ++nf) {
                    const int n = wc + nf * 16 + l15;
                    bfr[nf] = *(const bf16x8*)((const char*)Bsub + n * 128 +
                              ((ks * 64 + lhi * 16) ^ ((n & 7) << 4)));
                }
#pragma unroll
                for (int mf = 0; mf < 4; ++mf)
#pragma unroll
                    for (int nf = 0; nf < 4; ++nf)
                        acc[mf][nf] = __builtin_amdgcn_mfma_f32_16x16x32_bf16(
                            af[mf], bfr[nf], acc[mf][nf], 0, 0, 0);
            }
        }
    }

    // epilogue: C/D layout col = lane&15, row = (lane>>4)*4 + reg (m89/m91)
#pragma unroll
    for (int mf = 0; mf < 4; ++mf)
#pragma unroll
        for (int nf = 0; nf < 4; ++nf)
#pragma unroll
            for (int ri = 0; ri < 4; ++ri) {
                const int orow = brow + wr + mf * 16 + lhi * 4 + ri;
                const int ocol = bcol + wc + nf * 16 + l15;
                out[(size_t)orow * NOUT + ocol] = acc[mf][nf][ri];
            }
}

// ---------------------------------------------------------------------------
// Fallback (only if ws_size < 18.9 MB): correct but slow fp32 path.
// ---------------------------------------------------------------------------
__global__ void __launch_bounds__(256) naive_kernel(const float* __restrict__ x,
                                                    const float* __restrict__ cc,
                                                    float* __restrict__ out) {
    __shared__ float xs[1024];
    const int b = blockIdx.x;
    const int t = threadIdx.x;
#pragma unroll
    for (int j = 0; j < 4; ++j)
        xs[t * 4 + j] = fast_tanhf(x[(size_t)b * 1024 + t * 4 + j]);
    __syncthreads();

    const int o = t * 4;
    float a0 = 0.f, a1 = 0.f, a2 = 0.f, a3 = 0.f;
    for (int i = 0; i < 1024; ++i) {
        const float* cp = cc + (size_t)i * KTOT + (size_t)o * 9;
        const float xv = xs[i];
        float tpp = 1.0f, tp = xv;
        a0 += cp[0];  a1 += cp[9];  a2 += cp[18];  a3 += cp[27];
        a0 += xv * cp[1]; a1 += xv * cp[10]; a2 += xv * cp[19]; a3 += xv * cp[28];
#pragma unroll
        for (int d = 2; d <= 8; ++d) {
            const float cur = 2.0f * xv * tp - tpp;
            tpp = tp; tp = cur;
            a0 += cur * cp[d];      a1 += cur * cp[9 + d];
            a2 += cur * cp[18 + d]; a3 += cur * cp[27 + d];
        }
    }
    float* op = out + (size_t)b * NOUT + o;
    op[0] = a0; op[1] = a1; op[2] = a2; op[3] = a3;
}

extern "C" void kernel_launch(void* const* d_in, const int* in_sizes, int n_in,
                              void* d_out, int out_size, void* d_ws, size_t ws_size,
                              hipStream_t stream) {
    const float* x  = (const float*)d_in[0];
    const float* cc = (const float*)d_in[1];
    float* out = (float*)d_out;

    const size_t need = (size_t)KTOT * 1024 * sizeof(unsigned short);  // 18.9 MB
    if (ws_size >= need) {
        prep_kernel<<<512, 256, 0, stream>>>(cc, (unsigned short*)d_ws);
        cheby_gemm<<<512, 256, 0, stream>>>(x, (const unsigned short*)d_ws, out);
    } else {
        naive_kernel<<<8192, 256, 0, stream>>>(x, cc, out);
    }
}